// Round 2
// baseline (79.875 us; speedup 1.0000x reference)
//
#include <hip/hip_runtime.h>
#include <hip/hip_cooperative_groups.h>

namespace cg = cooperative_groups;

// RankLoss: loss = -mean_b( 1 / (sum_j sigmoid(x[b,j] - x[b,0]) + 0.5) )
// Only row i=0 of the pairwise matrix is consumed: O(B*N) = 32*2048 sigmoids.
//
// v3: single cooperative kernel node (v2 had rows-kernel + reduce-kernel;
// the reduce node was ~128 B of work paying a full node replay + kernel
// cold-start). 32 blocks x 256 threads: block b computes
// rr[b] = 1/(sum_j sigmoid(x[b,j]-x[b,0]) + 0.5) into d_ws, grid.sync()
// (device-scope barrier -> cross-XCD visibility of partials), then block 0
// wave 0 reduces the 32 partials and writes the loss.
// d_ws is re-poisoned each iteration but we write our 32 floats before
// reading them (within one kernel, ordered by the grid sync).

#define RL_B 32
#define RL_N 2048

__device__ __forceinline__ float sig(float d) {
    return 1.0f / (1.0f + __expf(-d));
}

__global__ __launch_bounds__(256) void RankLoss_73959336837390_fused(
    const float* __restrict__ x, float* __restrict__ partial,
    float* __restrict__ out) {
    const int b    = blockIdx.x;     // 0..31, one row per block
    const int tid  = threadIdx.x;    // 0..255 (4 waves)
    const int wave = tid >> 6;
    const int lane = tid & 63;

    __shared__ float ws[4];

    const float* __restrict__ row = x + b * RL_N;
    const float4* __restrict__ r4 = (const float4*)row;

    // Broadcast pivot (same address across each wave -> one transaction).
    const float x0 = row[0];

    // 2048 floats = 512 float4 over 256 threads: 2 per thread, coalesced.
    // Issue both loads before any compute.
    float4 v0 = r4[tid];
    float4 v1 = r4[tid + 256];

    float s = sig(v0.x - x0) + sig(v0.y - x0) + sig(v0.z - x0) + sig(v0.w - x0)
            + sig(v1.x - x0) + sig(v1.y - x0) + sig(v1.z - x0) + sig(v1.w - x0);

    // 64-lane butterfly within each wave, then LDS across the 4 waves.
    #pragma unroll
    for (int off = 32; off > 0; off >>= 1) s += __shfl_xor(s, off, 64);
    if (lane == 0) ws[wave] = s;
    __syncthreads();

    if (tid == 0) {
        float t = ws[0] + ws[1] + ws[2] + ws[3];
        partial[b] = 1.0f / (t + 0.5f);
    }
    __threadfence();          // make partial[b] device-visible before the barrier

    cg::this_grid().sync();   // cooperative grid-wide barrier (32 blocks)

    // Final reduction: block 0, wave 0. Same butterfly pattern as v2's
    // reduce kernel -> bitwise-identical result (absmax stayed 0.0).
    if (b == 0 && wave == 0) {
        float v = (lane < RL_B) ? partial[lane] : 0.0f;
        #pragma unroll
        for (int off = 32; off > 0; off >>= 1) v += __shfl_xor(v, off, 64);
        if (lane == 0) *out = -v / (float)RL_B;
    }
}

extern "C" void kernel_launch(void* const* d_in, const int* in_sizes, int n_in,
                              void* d_out, int out_size, void* d_ws, size_t ws_size,
                              hipStream_t stream) {
    const float* x = (const float*)d_in[0];
    float* out     = (float*)d_out;
    float* partial = (float*)d_ws;   // 32 floats; written before read

    void* args[] = {(void*)&x, (void*)&partial, (void*)&out};
    hipLaunchCooperativeKernel((const void*)RankLoss_73959336837390_fused,
                               dim3(RL_B), dim3(256), args, 0, stream);
}

// Round 4
// 55.442 us; speedup vs baseline: 1.4407x; 1.4407x over previous
//
#include <hip/hip_runtime.h>

// RankLoss: loss = -mean_b( 1 / (sum_j sigmoid(x[b,j] - x[b,0]) + 0.5) )
// Only row i=0 of the pairwise matrix is consumed: O(B*N) = 32*2048 sigmoids.
//
// v5 = v4 = v2 (R3 bench was an infra failure, not a kernel failure).
// History:
//   v1: 1 block x 1024 thr (single CU, serialized trans pipe)   60.8 us
//   v2: 32 blocks rows + tiny reduce node (2 graph nodes)       55.1 us
//   v3: cooperative single node -> NOT graph-capturable,
//       fell off the graph-replay path                          79.9 us  [REVERTED]
//   v4: revert to v2                                            (infra fail)
// Harness floor: ~40 us d_ws re-poison fill + ~11 us other resets; our two
// nodes cost ~3-4 us total (rows kernel is latency-bound on HBM-cold input
// because the 268 MB fill evicts L2+L3 every iteration).
// Do NOT use hipLaunchCooperativeKernel here: plain nodes replay in ~1 us,
// cooperative launches bypass the graph and cost ~25 us/iteration.

#define RL_B 32
#define RL_N 2048

__device__ __forceinline__ float sig(float d) {
    return 1.0f / (1.0f + __expf(-d));
}

__global__ __launch_bounds__(64) void RankLoss_73959336837390_rows(
    const float* __restrict__ x, float* __restrict__ partial) {
    const int b    = blockIdx.x;    // 0..31, one row pair-sum per block
    const int lane = threadIdx.x;   // 0..63, single wave

    const float* __restrict__ row = x + b * RL_N;
    const float4* __restrict__ r4 = (const float4*)row;

    // Broadcast pivot (same address across the wave -> one transaction).
    const float x0 = row[0];

    // 2048 floats = 512 float4 over 64 lanes: 8 per lane, coalesced
    // (lane + 64k). Issue all loads before any compute to overlap the
    // ~900-cycle cold-memory latency.
    float4 v[8];
    #pragma unroll
    for (int k = 0; k < 8; ++k) v[k] = r4[lane + (k << 6)];

    float s = 0.0f;
    #pragma unroll
    for (int k = 0; k < 8; ++k) {
        s += sig(v[k].x - x0) + sig(v[k].y - x0)
           + sig(v[k].z - x0) + sig(v[k].w - x0);
    }

    // 64-lane butterfly reduction (order identical to v1/v2 -> absmax 0.0).
    #pragma unroll
    for (int off = 32; off > 0; off >>= 1) s += __shfl_xor(s, off, 64);

    if (lane == 0) partial[b] = 1.0f / (s + 0.5f);
}

__global__ __launch_bounds__(64) void RankLoss_73959336837390_reduce(
    const float* __restrict__ partial, float* __restrict__ out) {
    const int lane = threadIdx.x;   // single wave
    float v = (lane < RL_B) ? partial[lane] : 0.0f;
    #pragma unroll
    for (int off = 32; off > 0; off >>= 1) v += __shfl_xor(v, off, 64);
    if (lane == 0) *out = -v / (float)RL_B;
}

extern "C" void kernel_launch(void* const* d_in, const int* in_sizes, int n_in,
                              void* d_out, int out_size, void* d_ws, size_t ws_size,
                              hipStream_t stream) {
    const float* x = (const float*)d_in[0];
    float* out     = (float*)d_out;
    float* partial = (float*)d_ws;   // 32 floats; written before read

    RankLoss_73959336837390_rows<<<RL_B, 64, 0, stream>>>(x, partial);
    RankLoss_73959336837390_reduce<<<1, 64, 0, stream>>>(partial, out);
}